// Round 1
// baseline (6792.118 us; speedup 1.0000x reference)
//
#include <hip/hip_runtime.h>

#define Nn 100000
#define Ee 600000
#define Hh 128
#define NP 100096  // padded node rows: multiple of 64

static __device__ __forceinline__ float sigmoidf_(float x) {
  return 1.0f / (1.0f + __expf(-x));
}
static __device__ __forceinline__ float tanh_fast(float x) {
  // tanh(x) = 1 - 2/(exp(2x)+1); exp->inf => 1, exp->0 => -1
  return 1.0f - 2.0f / (__expf(2.0f * x) + 1.0f);
}

__global__ void zero_kernel(int* __restrict__ a, int* __restrict__ b, int n) {
  int i = blockIdx.x * 256 + threadIdx.x;
  if (i < n) { a[i] = 0; b[i] = 0; }
}

__global__ void count_kernel(const int* __restrict__ ei, int* __restrict__ degi,
                             int* __restrict__ cnt) {
  int e = blockIdx.x * 256 + threadIdx.x;
  if (e >= Ee) return;
  int r = ei[e], c = ei[Ee + e];
  atomicAdd(&degi[r], 1);
  atomicAdd(&degi[c], 1);
  atomicAdd(&cnt[c], 1);
}

__global__ void dis_kernel(const int* __restrict__ degi, float* __restrict__ dis) {
  int i = blockIdx.x * 256 + threadIdx.x;
  if (i < Nn) dis[i] = rsqrtf((float)degi[i] + 1.0f);
}

__global__ void scan_partial(const int* __restrict__ cnt, int* __restrict__ bsum) {
  __shared__ int s[256];
  int i = blockIdx.x * 256 + threadIdx.x;
  s[threadIdx.x] = (i < Nn) ? cnt[i] : 0;
  __syncthreads();
  for (int off = 128; off > 0; off >>= 1) {
    if (threadIdx.x < off) s[threadIdx.x] += s[threadIdx.x + off];
    __syncthreads();
  }
  if (threadIdx.x == 0) bsum[blockIdx.x] = s[0];
}

__global__ void scan_bsums(const int* __restrict__ bsum, int* __restrict__ bpre, int nb) {
  __shared__ int s[512];
  int t = threadIdx.x;
  s[t] = (t < nb) ? bsum[t] : 0;
  __syncthreads();
  for (int off = 1; off < 512; off <<= 1) {
    int u = (t >= off) ? s[t - off] : 0;
    __syncthreads();
    s[t] += u;
    __syncthreads();
  }
  if (t < nb) bpre[t] = (t == 0) ? 0 : s[t - 1];
}

__global__ void scan_final(const int* __restrict__ cnt, const int* __restrict__ bpre,
                           int* __restrict__ rowptr, int* __restrict__ cursor) {
  __shared__ int s[256];
  int t = threadIdx.x;
  int i = blockIdx.x * 256 + t;
  int v = (i < Nn) ? cnt[i] : 0;
  s[t] = v;
  __syncthreads();
  for (int off = 1; off < 256; off <<= 1) {
    int u = (t >= off) ? s[t - off] : 0;
    __syncthreads();
    s[t] += u;
    __syncthreads();
  }
  int excl = s[t] - v;
  int base = bpre[blockIdx.x];
  if (i < Nn) { rowptr[i] = base + excl; cursor[i] = base + excl; }
  if (i == Nn - 1) rowptr[Nn] = base + excl + v;
}

__global__ void fill_kernel(const int* __restrict__ ei, const float* __restrict__ dis,
                            int* __restrict__ cursor, int* __restrict__ csr_src,
                            float* __restrict__ csr_w) {
  int e = blockIdx.x * 256 + threadIdx.x;
  if (e >= Ee) return;
  int r = ei[e], c = ei[Ee + e];
  int p = atomicAdd(&cursor[c], 1);
  csr_src[p] = r;
  csr_w[p] = dis[r] * dis[c];
}

__global__ void h0_kernel(const float* __restrict__ X, const float* __restrict__ W0,
                          const float* __restrict__ b0, float* __restrict__ h,
                          float* __restrict__ hmax) {
  int t = blockIdx.x * 256 + threadIdx.x;
  int i = t >> 7, d = t & 127;
  if (i >= NP) return;
  float v = 0.0f;
  if (i < Nn) {
    float x0 = X[i * 3 + 0], x1 = X[i * 3 + 1], x2 = X[i * 3 + 2];
    v = fmaf(x0, W0[d * 3 + 0], fmaf(x1, W0[d * 3 + 1], fmaf(x2, W0[d * 3 + 2], b0[d])));
    v = v > 0.0f ? v : 0.01f * v;
  }
  size_t gi = (size_t)i * Hh + d;
  h[gi] = v;
  hmax[gi] = -1e30f;
}

__global__ __launch_bounds__(256) void agg_kernel(const float* __restrict__ h,
    const int* __restrict__ csr_src, const float* __restrict__ csr_w,
    const int* __restrict__ rowptr, float* __restrict__ hag) {
  int t = blockIdx.x * 256 + threadIdx.x;
  int node = t >> 5, lane = t & 31;
  if (node >= NP) return;
  float ax = 0.f, ay = 0.f, az = 0.f, aw = 0.f;
  if (node < Nn) {
    int e0 = rowptr[node], e1 = rowptr[node + 1];
    for (int e = e0; e < e1; ++e) {
      int src = csr_src[e];
      float w = csr_w[e];
      float4 hv = *(const float4*)(h + (size_t)src * Hh + lane * 4);
      ax = fmaf(w, hv.x, ax);
      ay = fmaf(w, hv.y, ay);
      az = fmaf(w, hv.z, az);
      aw = fmaf(w, hv.w, aw);
    }
  }
  float4 o;
  o.x = ax; o.y = ay; o.z = az; o.w = aw;
  *(float4*)(hag + (size_t)node * Hh + lane * 4) = o;
}

// Fused GRU cell: 64 nodes/block, 256 threads.
// Per thread: 4 rows x 2 cols micro-tile for 4 accumulator sets
// (r-gate sum, z-gate sum, xn, hn), K=128.
__global__ __launch_bounds__(256, 2) void gru_kernel(
    const float* __restrict__ hag, float* __restrict__ h, float* __restrict__ hmax,
    const float* __restrict__ Wih, const float* __restrict__ Whh,
    const float* __restrict__ bih, const float* __restrict__ bhh) {
  __shared__ float As[64][128];
  __shared__ float Hs[64][128];
  const int tid = threadIdx.x;
  const size_t b0r = (size_t)blockIdx.x * 64;

#pragma unroll
  for (int it = 0; it < 8; ++it) {
    int idx = tid + it * 256;
    int r = idx >> 5, c4 = idx & 31;
    *(float4*)&As[r][c4 * 4] = *(const float4*)(hag + (b0r + r) * Hh + c4 * 4);
    *(float4*)&Hs[r][c4 * 4] = *(const float4*)(h + (b0r + r) * Hh + c4 * 4);
  }
  __syncthreads();

  const int cg = tid & 15, rg = tid >> 4;
  const int r0 = rg * 4;

  for (int cc = 0; cc < 4; ++cc) {
    const int c0 = cc * 32 + cg * 2;
    float ar[4][2] = {{0.f, 0.f}, {0.f, 0.f}, {0.f, 0.f}, {0.f, 0.f}};
    float az[4][2] = {{0.f, 0.f}, {0.f, 0.f}, {0.f, 0.f}, {0.f, 0.f}};
    float axn[4][2] = {{0.f, 0.f}, {0.f, 0.f}, {0.f, 0.f}, {0.f, 0.f}};
    float ahn[4][2] = {{0.f, 0.f}, {0.f, 0.f}, {0.f, 0.f}, {0.f, 0.f}};

    const float* pxr = Wih + (size_t)c0 * Hh;
    const float* pxz = Wih + (size_t)(128 + c0) * Hh;
    const float* pxn = Wih + (size_t)(256 + c0) * Hh;
    const float* phr = Whh + (size_t)c0 * Hh;
    const float* phz = Whh + (size_t)(128 + c0) * Hh;
    const float* phn = Whh + (size_t)(256 + c0) * Hh;

    for (int k = 0; k < 128; k += 4) {
      float4 wxr[2], wxz[2], wxn[2], whr[2], whz[2], whn[2];
#pragma unroll
      for (int j = 0; j < 2; ++j) {
        wxr[j] = *(const float4*)(pxr + (size_t)j * Hh + k);
        wxz[j] = *(const float4*)(pxz + (size_t)j * Hh + k);
        wxn[j] = *(const float4*)(pxn + (size_t)j * Hh + k);
        whr[j] = *(const float4*)(phr + (size_t)j * Hh + k);
        whz[j] = *(const float4*)(phz + (size_t)j * Hh + k);
        whn[j] = *(const float4*)(phn + (size_t)j * Hh + k);
      }
#pragma unroll
      for (int i = 0; i < 4; ++i) {
        float4 a = *(const float4*)&As[r0 + i][k];
        float4 hh = *(const float4*)&Hs[r0 + i][k];
#pragma unroll
        for (int j = 0; j < 2; ++j) {
          ar[i][j] = fmaf(a.x, wxr[j].x, fmaf(a.y, wxr[j].y, fmaf(a.z, wxr[j].z, fmaf(a.w, wxr[j].w, ar[i][j]))));
          ar[i][j] = fmaf(hh.x, whr[j].x, fmaf(hh.y, whr[j].y, fmaf(hh.z, whr[j].z, fmaf(hh.w, whr[j].w, ar[i][j]))));
          az[i][j] = fmaf(a.x, wxz[j].x, fmaf(a.y, wxz[j].y, fmaf(a.z, wxz[j].z, fmaf(a.w, wxz[j].w, az[i][j]))));
          az[i][j] = fmaf(hh.x, whz[j].x, fmaf(hh.y, whz[j].y, fmaf(hh.z, whz[j].z, fmaf(hh.w, whz[j].w, az[i][j]))));
          axn[i][j] = fmaf(a.x, wxn[j].x, fmaf(a.y, wxn[j].y, fmaf(a.z, wxn[j].z, fmaf(a.w, wxn[j].w, axn[i][j]))));
          ahn[i][j] = fmaf(hh.x, whn[j].x, fmaf(hh.y, whn[j].y, fmaf(hh.z, whn[j].z, fmaf(hh.w, whn[j].w, ahn[i][j]))));
        }
      }
    }

#pragma unroll
    for (int j = 0; j < 2; ++j) {
      const int c = c0 + j;
      const float br = bih[c] + bhh[c];
      const float bz = bih[128 + c] + bhh[128 + c];
      const float bxn = bih[256 + c];
      const float bhn = bhh[256 + c];
#pragma unroll
      for (int i = 0; i < 4; ++i) {
        float rr = sigmoidf_(ar[i][j] + br);
        float zz = sigmoidf_(az[i][j] + bz);
        float nn = tanh_fast(axn[i][j] + bxn + rr * (ahn[i][j] + bhn));
        float hold = Hs[r0 + i][c];
        float hnew = (1.0f - zz) * nn + zz * hold;
        size_t gi = (b0r + r0 + i) * Hh + c;
        h[gi] = hnew;
        hmax[gi] = fmaxf(hmax[gi], hnew);
      }
    }
  }
}

__global__ __launch_bounds__(256) void mlp_kernel(const float* __restrict__ hmax,
    const float* __restrict__ Wm1, const float* __restrict__ bm1,
    const float* __restrict__ Wm2, const float* __restrict__ bm2,
    float* __restrict__ out) {
  int wave = threadIdx.x >> 6, lane = threadIdx.x & 63;
  int node = blockIdx.x * 4 + wave;
  if (node >= Nn) return;
  float acc = 0.f;
  const float4* wrow = (const float4*)(Wm1 + (size_t)lane * Hh);
  const float4* hrow = (const float4*)(hmax + (size_t)node * Hh);
  for (int k4 = 0; k4 < 32; ++k4) {
    float4 w = wrow[k4];
    float4 hv = hrow[k4];
    acc = fmaf(w.x, hv.x, acc);
    acc = fmaf(w.y, hv.y, acc);
    acc = fmaf(w.z, hv.z, acc);
    acc = fmaf(w.w, hv.w, acc);
  }
  float hid = acc + bm1[lane];
  hid = hid > 0.f ? hid : 0.01f * hid;
  float v = hid * Wm2[lane];
  for (int off = 32; off > 0; off >>= 1) v += __shfl_down(v, off);
  if (lane == 0) out[node] = v + bm2[0];
}

extern "C" void kernel_launch(void* const* d_in, const int* in_sizes, int n_in,
                              void* d_out, int out_size, void* d_ws, size_t ws_size,
                              hipStream_t stream) {
  const float* X = (const float*)d_in[0];
  const int* ei = (const int*)d_in[1];
  const float* W0 = (const float*)d_in[2];
  const float* b0 = (const float*)d_in[3];
  const float* Wih = (const float*)d_in[4];
  const float* Whh = (const float*)d_in[5];
  const float* bih = (const float*)d_in[6];
  const float* bhh = (const float*)d_in[7];
  const float* Wm1 = (const float*)d_in[8];
  const float* bm1 = (const float*)d_in[9];
  const float* Wm2 = (const float*)d_in[10];
  const float* bm2 = (const float*)d_in[11];
  float* out = (float*)d_out;

  char* ws = (char*)d_ws;
  size_t off = 0;
  auto alloc = [&](size_t bytes) -> void* {
    void* p = ws + off;
    off = (off + bytes + 255) & ~(size_t)255;
    return p;
  };
  float* h = (float*)alloc((size_t)NP * Hh * 4);
  float* hag = (float*)alloc((size_t)NP * Hh * 4);
  float* hmax = (float*)alloc((size_t)NP * Hh * 4);
  float* dis = (float*)alloc((size_t)Nn * 4);
  int* degi = (int*)alloc((size_t)Nn * 4);
  int* cnt = (int*)alloc((size_t)Nn * 4);
  int* rowptr = (int*)alloc((size_t)(Nn + 1) * 4);
  int* cursor = (int*)alloc((size_t)Nn * 4);
  int* bsum = (int*)alloc(512 * 4);
  int* bpre = (int*)alloc(512 * 4);
  int* csr_src = (int*)alloc((size_t)Ee * 4);
  float* csr_w = (float*)alloc((size_t)Ee * 4);
  (void)ws_size;
  (void)in_sizes;
  (void)n_in;
  (void)out_size;

  const int NB = (Nn + 255) / 256;  // 391
  const int EB = (Ee + 255) / 256;  // 2344

  zero_kernel<<<NB, 256, 0, stream>>>(degi, cnt, Nn);
  count_kernel<<<EB, 256, 0, stream>>>(ei, degi, cnt);
  dis_kernel<<<NB, 256, 0, stream>>>(degi, dis);
  scan_partial<<<NB, 256, 0, stream>>>(cnt, bsum);
  scan_bsums<<<1, 512, 0, stream>>>(bsum, bpre, NB);
  scan_final<<<NB, 256, 0, stream>>>(cnt, bpre, rowptr, cursor);
  fill_kernel<<<EB, 256, 0, stream>>>(ei, dis, cursor, csr_src, csr_w);
  h0_kernel<<<(NP * Hh) / 256, 256, 0, stream>>>(X, W0, b0, h, hmax);

  for (int it = 0; it < 5; ++it) {
    agg_kernel<<<(NP * 32) / 256, 256, 0, stream>>>(h, csr_src, csr_w, rowptr, hag);
    gru_kernel<<<NP / 64, 256, 0, stream>>>(hag, h, hmax, Wih, Whh, bih, bhh);
  }

  mlp_kernel<<<(Nn + 3) / 4, 256, 0, stream>>>(hmax, Wm1, bm1, Wm2, bm2, out);
}

// Round 2
// 1666.100 us; speedup vs baseline: 4.0767x; 4.0767x over previous
//
#include <hip/hip_runtime.h>

#define Nn 100000
#define Ee 600000
#define Hh 128
#define NP 100096  // padded node rows: multiple of 64

typedef short bf16x8 __attribute__((ext_vector_type(8)));
typedef float f32x4 __attribute__((ext_vector_type(4)));

static __device__ __forceinline__ float sigmoidf_(float x) {
  return 1.0f / (1.0f + __expf(-x));
}
static __device__ __forceinline__ float tanh_fast(float x) {
  return 1.0f - 2.0f / (__expf(2.0f * x) + 1.0f);
}
// round-to-nearest-even fp32 -> bf16 bits
static __device__ __forceinline__ ushort f2bf(float v) {
  unsigned u = __float_as_uint(v);
  unsigned r = (u + 0x7fffu + ((u >> 16) & 1u)) >> 16;
  return (ushort)r;
}
static __device__ __forceinline__ float bf2f(ushort b) {
  return __uint_as_float(((unsigned)b) << 16);
}

__global__ void zero_kernel(int* __restrict__ a, int* __restrict__ b, int n) {
  int i = blockIdx.x * 256 + threadIdx.x;
  if (i < n) { a[i] = 0; b[i] = 0; }
}

__global__ void count_kernel(const int* __restrict__ ei, int* __restrict__ degi,
                             int* __restrict__ cnt) {
  int e = blockIdx.x * 256 + threadIdx.x;
  if (e >= Ee) return;
  int r = ei[e], c = ei[Ee + e];
  atomicAdd(&degi[r], 1);
  atomicAdd(&degi[c], 1);
  atomicAdd(&cnt[c], 1);
}

__global__ void dis_kernel(const int* __restrict__ degi, float* __restrict__ dis) {
  int i = blockIdx.x * 256 + threadIdx.x;
  if (i < Nn) dis[i] = rsqrtf((float)degi[i] + 1.0f);
}

__global__ void scan_partial(const int* __restrict__ cnt, int* __restrict__ bsum) {
  __shared__ int s[256];
  int i = blockIdx.x * 256 + threadIdx.x;
  s[threadIdx.x] = (i < Nn) ? cnt[i] : 0;
  __syncthreads();
  for (int off = 128; off > 0; off >>= 1) {
    if (threadIdx.x < off) s[threadIdx.x] += s[threadIdx.x + off];
    __syncthreads();
  }
  if (threadIdx.x == 0) bsum[blockIdx.x] = s[0];
}

__global__ void scan_bsums(const int* __restrict__ bsum, int* __restrict__ bpre, int nb) {
  __shared__ int s[512];
  int t = threadIdx.x;
  s[t] = (t < nb) ? bsum[t] : 0;
  __syncthreads();
  for (int off = 1; off < 512; off <<= 1) {
    int u = (t >= off) ? s[t - off] : 0;
    __syncthreads();
    s[t] += u;
    __syncthreads();
  }
  if (t < nb) bpre[t] = (t == 0) ? 0 : s[t - 1];
}

__global__ void scan_final(const int* __restrict__ cnt, const int* __restrict__ bpre,
                           int* __restrict__ rowptr, int* __restrict__ cursor) {
  __shared__ int s[256];
  int t = threadIdx.x;
  int i = blockIdx.x * 256 + t;
  int v = (i < Nn) ? cnt[i] : 0;
  s[t] = v;
  __syncthreads();
  for (int off = 1; off < 256; off <<= 1) {
    int u = (t >= off) ? s[t - off] : 0;
    __syncthreads();
    s[t] += u;
    __syncthreads();
  }
  int excl = s[t] - v;
  int base = bpre[blockIdx.x];
  if (i < Nn) { rowptr[i] = base + excl; cursor[i] = base + excl; }
  if (i == Nn - 1) rowptr[Nn] = base + excl + v;
}

__global__ void fill_kernel(const int* __restrict__ ei, const float* __restrict__ dis,
                            int* __restrict__ cursor, int* __restrict__ csr_src,
                            float* __restrict__ csr_w) {
  int e = blockIdx.x * 256 + threadIdx.x;
  if (e >= Ee) return;
  int r = ei[e], c = ei[Ee + e];
  int p = atomicAdd(&cursor[c], 1);
  csr_src[p] = r;
  csr_w[p] = dis[r] * dis[c];
}

// Pack weights into fragment-major split-bf16:
// Bp[kc][fid][g][c16][j], fid = gate*8+f, gate 0=r,1=z,2=n(x-part for kc<4, h-part kc>=4)
// value at k = kc*32 + g*8 + j, col c = (fid&7)*16 + c16, weight row = gate*128 + c.
__global__ void pack_kernel(const float* __restrict__ Wih, const float* __restrict__ Whh,
                            ushort* __restrict__ Bhi, ushort* __restrict__ Blo) {
  int t = blockIdx.x * 256 + threadIdx.x;  // 8*24*4*16 = 12288 threads
  if (t >= 8 * 24 * 4 * 16) return;
  int c16 = t & 15;
  int g = (t >> 4) & 3;
  int fid = (t >> 6) % 24;
  int kc = t / (24 * 64);
  int gate = fid >> 3, f = fid & 7;
  int c = f * 16 + c16;
  int wrow = gate * 128 + c;
  size_t base = (size_t)t * 8;
#pragma unroll
  for (int j = 0; j < 8; ++j) {
    int k = kc * 32 + g * 8 + j;
    float v = (k < 128) ? Wih[wrow * 128 + k] : Whh[wrow * 128 + (k - 128)];
    ushort hi = f2bf(v);
    Bhi[base + j] = hi;
    Blo[base + j] = f2bf(v - bf2f(hi));
  }
}

__global__ void h0_kernel(const float* __restrict__ X, const float* __restrict__ W0,
                          const float* __restrict__ b0, float* __restrict__ h,
                          float* __restrict__ hmax, ushort* __restrict__ Ahi,
                          ushort* __restrict__ Alo) {
  int t = blockIdx.x * 256 + threadIdx.x;
  int i = t >> 7, d = t & 127;
  if (i >= NP) return;
  float v = 0.0f;
  if (i < Nn) {
    float x0 = X[i * 3 + 0], x1 = X[i * 3 + 1], x2 = X[i * 3 + 2];
    v = fmaf(x0, W0[d * 3 + 0], fmaf(x1, W0[d * 3 + 1], fmaf(x2, W0[d * 3 + 2], b0[d])));
    v = v > 0.0f ? v : 0.01f * v;
  }
  size_t gi = (size_t)i * Hh + d;
  h[gi] = v;
  hmax[gi] = -1e30f;
  ushort hi = f2bf(v);
  size_t ai = (size_t)i * 256 + 128 + d;
  Ahi[ai] = hi;
  Alo[ai] = f2bf(v - bf2f(hi));
}

// Gather: out rows written as split-bf16 into A cols [0,128)
__global__ __launch_bounds__(256) void agg_kernel(const float* __restrict__ h,
    const int* __restrict__ csr_src, const float* __restrict__ csr_w,
    const int* __restrict__ rowptr, ushort* __restrict__ Ahi, ushort* __restrict__ Alo) {
  int t = blockIdx.x * 256 + threadIdx.x;
  int node = t >> 5, lane = t & 31;
  if (node >= NP) return;
  float ax = 0.f, ay = 0.f, az = 0.f, aw = 0.f;
  if (node < Nn) {
    int e0 = rowptr[node], e1 = rowptr[node + 1];
    for (int e = e0; e < e1; ++e) {
      int src = csr_src[e];
      float w = csr_w[e];
      float4 hv = *(const float4*)(h + (size_t)src * Hh + lane * 4);
      ax = fmaf(w, hv.x, ax);
      ay = fmaf(w, hv.y, ay);
      az = fmaf(w, hv.z, az);
      aw = fmaf(w, hv.w, aw);
    }
  }
  float a4[4] = {ax, ay, az, aw};
  ushort hi[4], lo[4];
#pragma unroll
  for (int j = 0; j < 4; ++j) {
    hi[j] = f2bf(a4[j]);
    lo[j] = f2bf(a4[j] - bf2f(hi[j]));
  }
  size_t base = (size_t)node * 256 + lane * 4;
  *(ushort4*)(Ahi + base) = make_ushort4(hi[0], hi[1], hi[2], hi[3]);
  *(ushort4*)(Alo + base) = make_ushort4(lo[0], lo[1], lo[2], lo[3]);
}

// ---- MFMA GRU ----
// Block = 64 nodes, 256 threads = 4 waves. Wave w owns cols [32w, 32w+32) of each gate.
// A = [hag | h] split bf16, row-major 256/row. B pre-packed (pack_kernel).
// 3-pass split per fragment pair: AhiBhi + AhiBlo + AloBhi.

#define DO_GATE(GB, ACC)                                                              \
  {                                                                                   \
    bf16x8 bH[2], bL[2];                                                              \
    _Pragma("unroll") for (int cf = 0; cf < 2; ++cf) {                                \
      size_t boff = (((size_t)(kc * 24 + (GB)*8 + wave * 2 + cf) * 4 + g) * 16 + c16) * 8; \
      bH[cf] = *(const bf16x8*)(Bhi + boff);                                          \
      bL[cf] = *(const bf16x8*)(Blo + boff);                                          \
    }                                                                                 \
    _Pragma("unroll") for (int cf = 0; cf < 2; ++cf)                                  \
        _Pragma("unroll") for (int rf = 0; rf < 4; ++rf)                              \
            ACC[rf][cf] = __builtin_amdgcn_mfma_f32_16x16x32_bf16(aH[rf], bH[cf], ACC[rf][cf], 0, 0, 0); \
    _Pragma("unroll") for (int cf = 0; cf < 2; ++cf)                                  \
        _Pragma("unroll") for (int rf = 0; rf < 4; ++rf)                              \
            ACC[rf][cf] = __builtin_amdgcn_mfma_f32_16x16x32_bf16(aH[rf], bL[cf], ACC[rf][cf], 0, 0, 0); \
    _Pragma("unroll") for (int cf = 0; cf < 2; ++cf)                                  \
        _Pragma("unroll") for (int rf = 0; rf < 4; ++rf)                              \
            ACC[rf][cf] = __builtin_amdgcn_mfma_f32_16x16x32_bf16(aL[rf], bH[cf], ACC[rf][cf], 0, 0, 0); \
  }

#define KC_STEP(ACCN)                                                                 \
  {                                                                                   \
    bf16x8 aH[4], aL[4];                                                              \
    size_t aoff = arowoff + (size_t)kc * 32 + (size_t)g * 8;                          \
    _Pragma("unroll") for (int rf = 0; rf < 4; ++rf) {                                \
      aH[rf] = *(const bf16x8*)(Ah + aoff + (size_t)rf * 4096);                       \
      aL[rf] = *(const bf16x8*)(Al + aoff + (size_t)rf * 4096);                       \
    }                                                                                 \
    DO_GATE(0, accR)                                                                  \
    DO_GATE(1, accZ)                                                                  \
    DO_GATE(2, ACCN)                                                                  \
  }

__global__ __launch_bounds__(256, 2) void gru_mfma(
    ushort* __restrict__ Ah, ushort* __restrict__ Al,
    const ushort* __restrict__ Bhi, const ushort* __restrict__ Blo,
    float* __restrict__ h, float* __restrict__ hmax,
    const float* __restrict__ bih, const float* __restrict__ bhh) {
  const int tid = threadIdx.x;
  const int wave = tid >> 6, lane = tid & 63;
  const int g = lane >> 4, c16 = lane & 15;
  const long rowbase = (long)blockIdx.x * 64;
  const size_t arowoff = (size_t)(rowbase + c16) * 256;

  f32x4 accR[4][2], accZ[4][2], accXN[4][2], accHN[4][2];
#pragma unroll
  for (int rf = 0; rf < 4; ++rf)
#pragma unroll
    for (int cf = 0; cf < 2; ++cf) {
      accR[rf][cf] = (f32x4){0.f, 0.f, 0.f, 0.f};
      accZ[rf][cf] = (f32x4){0.f, 0.f, 0.f, 0.f};
      accXN[rf][cf] = (f32x4){0.f, 0.f, 0.f, 0.f};
      accHN[rf][cf] = (f32x4){0.f, 0.f, 0.f, 0.f};
    }

#pragma unroll
  for (int kc = 0; kc < 4; ++kc) KC_STEP(accXN)
#pragma unroll
  for (int kc = 4; kc < 8; ++kc) KC_STEP(accHN)

  // epilogue: wave w, col c = (w*2+cf)*16 + c16; row = rowbase + rf*16 + g*4 + reg
#pragma unroll
  for (int cf = 0; cf < 2; ++cf) {
    const int c = (wave * 2 + cf) * 16 + c16;
    const float br = bih[c] + bhh[c];
    const float bz = bih[128 + c] + bhh[128 + c];
    const float bxn = bih[256 + c];
    const float bhn = bhh[256 + c];
#pragma unroll
    for (int rf = 0; rf < 4; ++rf) {
      const long row0 = rowbase + rf * 16 + g * 4;
#pragma unroll
      for (int reg = 0; reg < 4; ++reg) {
        const long row = row0 + reg;
        float rr = sigmoidf_(accR[rf][cf][reg] + br);
        float zz = sigmoidf_(accZ[rf][cf][reg] + bz);
        float nn = tanh_fast(accXN[rf][cf][reg] + bxn + rr * (accHN[rf][cf][reg] + bhn));
        size_t gi = (size_t)row * Hh + c;
        float hold = h[gi];
        float hnew = (1.0f - zz) * nn + zz * hold;
        h[gi] = hnew;
        hmax[gi] = fmaxf(hmax[gi], hnew);
        ushort hi = f2bf(hnew);
        size_t ai = (size_t)row * 256 + 128 + c;
        Ah[ai] = hi;
        Al[ai] = f2bf(hnew - bf2f(hi));
      }
    }
  }
}

__global__ __launch_bounds__(256) void mlp_kernel(const float* __restrict__ hmax,
    const float* __restrict__ Wm1, const float* __restrict__ bm1,
    const float* __restrict__ Wm2, const float* __restrict__ bm2,
    float* __restrict__ out) {
  int wave = threadIdx.x >> 6, lane = threadIdx.x & 63;
  int node = blockIdx.x * 4 + wave;
  if (node >= Nn) return;
  float acc = 0.f;
  const float4* wrow = (const float4*)(Wm1 + (size_t)lane * Hh);
  const float4* hrow = (const float4*)(hmax + (size_t)node * Hh);
  for (int k4 = 0; k4 < 32; ++k4) {
    float4 w = wrow[k4];
    float4 hv = hrow[k4];
    acc = fmaf(w.x, hv.x, acc);
    acc = fmaf(w.y, hv.y, acc);
    acc = fmaf(w.z, hv.z, acc);
    acc = fmaf(w.w, hv.w, acc);
  }
  float hid = acc + bm1[lane];
  hid = hid > 0.f ? hid : 0.01f * hid;
  float v = hid * Wm2[lane];
  for (int off = 32; off > 0; off >>= 1) v += __shfl_down(v, off);
  if (lane == 0) out[node] = v + bm2[0];
}

extern "C" void kernel_launch(void* const* d_in, const int* in_sizes, int n_in,
                              void* d_out, int out_size, void* d_ws, size_t ws_size,
                              hipStream_t stream) {
  const float* X = (const float*)d_in[0];
  const int* ei = (const int*)d_in[1];
  const float* W0 = (const float*)d_in[2];
  const float* b0 = (const float*)d_in[3];
  const float* Wih = (const float*)d_in[4];
  const float* Whh = (const float*)d_in[5];
  const float* bih = (const float*)d_in[6];
  const float* bhh = (const float*)d_in[7];
  const float* Wm1 = (const float*)d_in[8];
  const float* bm1 = (const float*)d_in[9];
  const float* Wm2 = (const float*)d_in[10];
  const float* bm2 = (const float*)d_in[11];
  float* out = (float*)d_out;

  char* ws = (char*)d_ws;
  size_t off = 0;
  auto alloc = [&](size_t bytes) -> void* {
    void* p = ws + off;
    off = (off + bytes + 255) & ~(size_t)255;
    return p;
  };
  float* h = (float*)alloc((size_t)NP * Hh * 4);
  float* hmax = (float*)alloc((size_t)NP * Hh * 4);
  ushort* Ahi = (ushort*)alloc((size_t)NP * 256 * 2);
  ushort* Alo = (ushort*)alloc((size_t)NP * 256 * 2);
  ushort* Bhi = (ushort*)alloc((size_t)8 * 24 * 4 * 16 * 8 * 2);
  ushort* Blo = (ushort*)alloc((size_t)8 * 24 * 4 * 16 * 8 * 2);
  float* dis = (float*)alloc((size_t)Nn * 4);
  int* degi = (int*)alloc((size_t)Nn * 4);
  int* cnt = (int*)alloc((size_t)Nn * 4);
  int* rowptr = (int*)alloc((size_t)(Nn + 1) * 4);
  int* cursor = (int*)alloc((size_t)Nn * 4);
  int* bsum = (int*)alloc(512 * 4);
  int* bpre = (int*)alloc(512 * 4);
  int* csr_src = (int*)alloc((size_t)Ee * 4);
  float* csr_w = (float*)alloc((size_t)Ee * 4);
  (void)ws_size;
  (void)in_sizes;
  (void)n_in;
  (void)out_size;

  const int NB = (Nn + 255) / 256;  // 391
  const int EB = (Ee + 255) / 256;  // 2344

  zero_kernel<<<NB, 256, 0, stream>>>(degi, cnt, Nn);
  count_kernel<<<EB, 256, 0, stream>>>(ei, degi, cnt);
  dis_kernel<<<NB, 256, 0, stream>>>(degi, dis);
  scan_partial<<<NB, 256, 0, stream>>>(cnt, bsum);
  scan_bsums<<<1, 512, 0, stream>>>(bsum, bpre, NB);
  scan_final<<<NB, 256, 0, stream>>>(cnt, bpre, rowptr, cursor);
  fill_kernel<<<EB, 256, 0, stream>>>(ei, dis, cursor, csr_src, csr_w);
  pack_kernel<<<48, 256, 0, stream>>>(Wih, Whh, Bhi, Blo);
  h0_kernel<<<(NP * Hh) / 256, 256, 0, stream>>>(X, W0, b0, h, hmax, Ahi, Alo);

  for (int it = 0; it < 5; ++it) {
    agg_kernel<<<(NP * 32) / 256, 256, 0, stream>>>(h, csr_src, csr_w, rowptr, Ahi, Alo);
    gru_mfma<<<NP / 64, 256, 0, stream>>>(Ahi, Alo, Bhi, Blo, h, hmax, bih, bhh);
  }

  mlp_kernel<<<(Nn + 3) / 4, 256, 0, stream>>>(hmax, Wm1, bm1, Wm2, bm2, out);
}

// Round 3
// 1347.645 us; speedup vs baseline: 5.0400x; 1.2363x over previous
//
#include <hip/hip_runtime.h>

#define Nn 100000
#define Ee 600000
#define Hh 128
#define NP 100096  // padded node rows: multiple of 64

typedef short bf16x8 __attribute__((ext_vector_type(8)));
typedef float f32x4 __attribute__((ext_vector_type(4)));

static __device__ __forceinline__ float sigmoidf_(float x) {
  return 1.0f / (1.0f + __expf(-x));
}
static __device__ __forceinline__ float tanh_fast(float x) {
  return 1.0f - 2.0f / (__expf(2.0f * x) + 1.0f);
}
// round-to-nearest-even fp32 -> bf16 bits
static __device__ __forceinline__ ushort f2bf(float v) {
  unsigned u = __float_as_uint(v);
  unsigned r = (u + 0x7fffu + ((u >> 16) & 1u)) >> 16;
  return (ushort)r;
}
static __device__ __forceinline__ float bf2f(ushort b) {
  return __uint_as_float(((unsigned)b) << 16);
}

__global__ void zero_kernel(int* __restrict__ a, int* __restrict__ b, int n) {
  int i = blockIdx.x * 256 + threadIdx.x;
  if (i < n) { a[i] = 0; b[i] = 0; }
}

__global__ void count_kernel(const int* __restrict__ ei, int* __restrict__ degi,
                             int* __restrict__ cnt) {
  int e = blockIdx.x * 256 + threadIdx.x;
  if (e >= Ee) return;
  int r = ei[e], c = ei[Ee + e];
  atomicAdd(&degi[r], 1);
  atomicAdd(&degi[c], 1);
  atomicAdd(&cnt[c], 1);
}

__global__ void dis_kernel(const int* __restrict__ degi, float* __restrict__ dis) {
  int i = blockIdx.x * 256 + threadIdx.x;
  if (i < Nn) dis[i] = rsqrtf((float)degi[i] + 1.0f);
}

__global__ void scan_partial(const int* __restrict__ cnt, int* __restrict__ bsum) {
  __shared__ int s[256];
  int i = blockIdx.x * 256 + threadIdx.x;
  s[threadIdx.x] = (i < Nn) ? cnt[i] : 0;
  __syncthreads();
  for (int off = 128; off > 0; off >>= 1) {
    if (threadIdx.x < off) s[threadIdx.x] += s[threadIdx.x + off];
    __syncthreads();
  }
  if (threadIdx.x == 0) bsum[blockIdx.x] = s[0];
}

__global__ void scan_bsums(const int* __restrict__ bsum, int* __restrict__ bpre, int nb) {
  __shared__ int s[512];
  int t = threadIdx.x;
  s[t] = (t < nb) ? bsum[t] : 0;
  __syncthreads();
  for (int off = 1; off < 512; off <<= 1) {
    int u = (t >= off) ? s[t - off] : 0;
    __syncthreads();
    s[t] += u;
    __syncthreads();
  }
  if (t < nb) bpre[t] = (t == 0) ? 0 : s[t - 1];
}

__global__ void scan_final(const int* __restrict__ cnt, const int* __restrict__ bpre,
                           int* __restrict__ rowptr, int* __restrict__ cursor) {
  __shared__ int s[256];
  int t = threadIdx.x;
  int i = blockIdx.x * 256 + t;
  int v = (i < Nn) ? cnt[i] : 0;
  s[t] = v;
  __syncthreads();
  for (int off = 1; off < 256; off <<= 1) {
    int u = (t >= off) ? s[t - off] : 0;
    __syncthreads();
    s[t] += u;
    __syncthreads();
  }
  int excl = s[t] - v;
  int base = bpre[blockIdx.x];
  if (i < Nn) { rowptr[i] = base + excl; cursor[i] = base + excl; }
  if (i == Nn - 1) rowptr[Nn] = base + excl + v;
}

__global__ void fill_kernel(const int* __restrict__ ei, const float* __restrict__ dis,
                            int* __restrict__ cursor, int* __restrict__ csr_src,
                            float* __restrict__ csr_w) {
  int e = blockIdx.x * 256 + threadIdx.x;
  if (e >= Ee) return;
  int r = ei[e], c = ei[Ee + e];
  int p = atomicAdd(&cursor[c], 1);
  csr_src[p] = r;
  csr_w[p] = dis[r] * dis[c];
}

// Pack GRU weights into fragment-major split-bf16:
// B[kc][fid][g][c16][j], fid = gate*8+f; k = kc*32+g*8+j, col c=(fid&7)*16+c16,
// weight row = gate*128 + c. kc<4 -> Wih, kc>=4 -> Whh.
__global__ void pack_kernel(const float* __restrict__ Wih, const float* __restrict__ Whh,
                            ushort* __restrict__ Bhi, ushort* __restrict__ Blo) {
  int t = blockIdx.x * 256 + threadIdx.x;  // 8*24*4*16 = 12288 threads
  if (t >= 8 * 24 * 4 * 16) return;
  int c16 = t & 15;
  int g = (t >> 4) & 3;
  int fid = (t >> 6) % 24;
  int kc = t / (24 * 64);
  int gate = fid >> 3, f = fid & 7;
  int c = f * 16 + c16;
  int wrow = gate * 128 + c;
  size_t base = (size_t)t * 8;
#pragma unroll
  for (int j = 0; j < 8; ++j) {
    int k = kc * 32 + g * 8 + j;
    float v = (k < 128) ? Wih[wrow * 128 + k] : Whh[wrow * 128 + (k - 128)];
    ushort hi = f2bf(v);
    Bhi[base + j] = hi;
    Blo[base + j] = f2bf(v - bf2f(hi));
  }
}

// Pack MLP W1 (64 x 128): Bm[kc][cf][g][c16][j], c = cf*16+c16, k = kc*32+g*8+j
__global__ void pack_mlp(const float* __restrict__ Wm1, ushort* __restrict__ Bh,
                         ushort* __restrict__ Bl) {
  int t = blockIdx.x * 256 + threadIdx.x;  // 4*4*4*16 = 1024
  if (t >= 1024) return;
  int c16 = t & 15;
  int g = (t >> 4) & 3;
  int cf = (t >> 6) & 3;
  int kc = t >> 8;
  int c = cf * 16 + c16;
  size_t base = (size_t)t * 8;
#pragma unroll
  for (int j = 0; j < 8; ++j) {
    int k = kc * 32 + g * 8 + j;
    float v = Wm1[c * 128 + k];
    ushort hi = f2bf(v);
    Bh[base + j] = hi;
    Bl[base + j] = f2bf(v - bf2f(hi));
  }
}

__global__ void h0_kernel(const float* __restrict__ X, const float* __restrict__ W0,
                          const float* __restrict__ b0, float* __restrict__ h,
                          ushort* __restrict__ Mh, ushort* __restrict__ Ml,
                          ushort* __restrict__ Ahi, ushort* __restrict__ Alo) {
  int t = blockIdx.x * 256 + threadIdx.x;
  int i = t >> 7, d = t & 127;
  if (i >= NP) return;
  float v = 0.0f;
  if (i < Nn) {
    float x0 = X[i * 3 + 0], x1 = X[i * 3 + 1], x2 = X[i * 3 + 2];
    v = fmaf(x0, W0[d * 3 + 0], fmaf(x1, W0[d * 3 + 1], fmaf(x2, W0[d * 3 + 2], b0[d])));
    v = v > 0.0f ? v : 0.01f * v;
  }
  size_t gi = (size_t)i * Hh + d;
  h[gi] = v;
  float m0 = -1e30f;
  ushort mhi = f2bf(m0);
  Mh[gi] = mhi;
  Ml[gi] = f2bf(m0 - bf2f(mhi));
  ushort hi = f2bf(v);
  size_t ai = (size_t)i * 256 + 128 + d;
  Ahi[ai] = hi;
  Alo[ai] = f2bf(v - bf2f(hi));
}

// Gather: out rows written as split-bf16 into A cols [0,128)
__global__ __launch_bounds__(256) void agg_kernel(const float* __restrict__ h,
    const int* __restrict__ csr_src, const float* __restrict__ csr_w,
    const int* __restrict__ rowptr, ushort* __restrict__ Ahi, ushort* __restrict__ Alo) {
  int t = blockIdx.x * 256 + threadIdx.x;
  int node = t >> 5, lane = t & 31;
  if (node >= NP) return;
  float ax = 0.f, ay = 0.f, az = 0.f, aw = 0.f;
  if (node < Nn) {
    int e0 = rowptr[node], e1 = rowptr[node + 1];
    for (int e = e0; e < e1; ++e) {
      int src = csr_src[e];
      float w = csr_w[e];
      float4 hv = *(const float4*)(h + (size_t)src * Hh + lane * 4);
      ax = fmaf(w, hv.x, ax);
      ay = fmaf(w, hv.y, ay);
      az = fmaf(w, hv.z, az);
      aw = fmaf(w, hv.w, aw);
    }
  }
  float a4[4] = {ax, ay, az, aw};
  ushort hi[4], lo[4];
#pragma unroll
  for (int j = 0; j < 4; ++j) {
    hi[j] = f2bf(a4[j]);
    lo[j] = f2bf(a4[j] - bf2f(hi[j]));
  }
  size_t base = (size_t)node * 256 + lane * 4;
  *(ushort4*)(Ahi + base) = make_ushort4(hi[0], hi[1], hi[2], hi[3]);
  *(ushort4*)(Alo + base) = make_ushort4(lo[0], lo[1], lo[2], lo[3]);
}

// ---- MFMA GRU ----
#define DO_GATE(GB, ACC)                                                              \
  {                                                                                   \
    bf16x8 bH[2], bL[2];                                                              \
    _Pragma("unroll") for (int cf = 0; cf < 2; ++cf) {                                \
      size_t boff = (((size_t)(kc * 24 + (GB)*8 + wave * 2 + cf) * 4 + g) * 16 + c16) * 8; \
      bH[cf] = *(const bf16x8*)(Bhi + boff);                                          \
      bL[cf] = *(const bf16x8*)(Blo + boff);                                          \
    }                                                                                 \
    _Pragma("unroll") for (int cf = 0; cf < 2; ++cf)                                  \
        _Pragma("unroll") for (int rf = 0; rf < 4; ++rf)                              \
            ACC[rf][cf] = __builtin_amdgcn_mfma_f32_16x16x32_bf16(aH[rf], bH[cf], ACC[rf][cf], 0, 0, 0); \
    _Pragma("unroll") for (int cf = 0; cf < 2; ++cf)                                  \
        _Pragma("unroll") for (int rf = 0; rf < 4; ++rf)                              \
            ACC[rf][cf] = __builtin_amdgcn_mfma_f32_16x16x32_bf16(aH[rf], bL[cf], ACC[rf][cf], 0, 0, 0); \
    _Pragma("unroll") for (int cf = 0; cf < 2; ++cf)                                  \
        _Pragma("unroll") for (int rf = 0; rf < 4; ++rf)                              \
            ACC[rf][cf] = __builtin_amdgcn_mfma_f32_16x16x32_bf16(aL[rf], bH[cf], ACC[rf][cf], 0, 0, 0); \
  }

#define KC_STEP(ACCN)                                                                 \
  {                                                                                   \
    bf16x8 aH[4], aL[4];                                                              \
    size_t aoff = arowoff + (size_t)kc * 32 + (size_t)g * 8;                          \
    _Pragma("unroll") for (int rf = 0; rf < 4; ++rf) {                                \
      aH[rf] = *(const bf16x8*)(Ah + aoff + (size_t)rf * 4096);                       \
      aL[rf] = *(const bf16x8*)(Al + aoff + (size_t)rf * 4096);                       \
    }                                                                                 \
    DO_GATE(0, accR)                                                                  \
    DO_GATE(1, accZ)                                                                  \
    DO_GATE(2, ACCN)                                                                  \
  }

__global__ __launch_bounds__(256, 2) void gru_mfma(
    ushort* __restrict__ Ah, ushort* __restrict__ Al,
    const ushort* __restrict__ Bhi, const ushort* __restrict__ Blo,
    float* __restrict__ h, ushort* __restrict__ Mh, ushort* __restrict__ Ml,
    const float* __restrict__ bih, const float* __restrict__ bhh) {
  const int tid = threadIdx.x;
  const int wave = tid >> 6, lane = tid & 63;
  const int g = lane >> 4, c16 = lane & 15;
  const long rowbase = (long)blockIdx.x * 64;
  const size_t arowoff = (size_t)(rowbase + c16) * 256;

  f32x4 accR[4][2], accZ[4][2], accXN[4][2], accHN[4][2];
#pragma unroll
  for (int rf = 0; rf < 4; ++rf)
#pragma unroll
    for (int cf = 0; cf < 2; ++cf) {
      accR[rf][cf] = (f32x4){0.f, 0.f, 0.f, 0.f};
      accZ[rf][cf] = (f32x4){0.f, 0.f, 0.f, 0.f};
      accXN[rf][cf] = (f32x4){0.f, 0.f, 0.f, 0.f};
      accHN[rf][cf] = (f32x4){0.f, 0.f, 0.f, 0.f};
    }

#pragma unroll
  for (int kc = 0; kc < 4; ++kc) KC_STEP(accXN)
#pragma unroll
  for (int kc = 4; kc < 8; ++kc) KC_STEP(accHN)

#pragma unroll
  for (int cf = 0; cf < 2; ++cf) {
    const int c = (wave * 2 + cf) * 16 + c16;
    const float br = bih[c] + bhh[c];
    const float bz = bih[128 + c] + bhh[128 + c];
    const float bxn = bih[256 + c];
    const float bhn = bhh[256 + c];
#pragma unroll
    for (int rf = 0; rf < 4; ++rf) {
      const long row0 = rowbase + rf * 16 + g * 4;
#pragma unroll
      for (int reg = 0; reg < 4; ++reg) {
        const long row = row0 + reg;
        float rr = sigmoidf_(accR[rf][cf][reg] + br);
        float zz = sigmoidf_(accZ[rf][cf][reg] + bz);
        float nn = tanh_fast(accXN[rf][cf][reg] + bxn + rr * (accHN[rf][cf][reg] + bhn));
        size_t gi = (size_t)row * Hh + c;
        float hold = h[gi];
        float hnew = (1.0f - zz) * nn + zz * hold;
        h[gi] = hnew;
        float mold = bf2f(Mh[gi]) + bf2f(Ml[gi]);
        float mnew = fmaxf(mold, hnew);
        ushort mhi = f2bf(mnew);
        Mh[gi] = mhi;
        Ml[gi] = f2bf(mnew - bf2f(mhi));
        ushort hi = f2bf(hnew);
        size_t ai = (size_t)row * 256 + 128 + c;
        Ah[ai] = hi;
        Al[ai] = f2bf(hnew - bf2f(hi));
      }
    }
  }
}

// ---- MFMA MLP ----
// Block = 64 nodes, 4 waves; wave w owns cols [16w, 16w+16) of hid (64 cols).
__global__ __launch_bounds__(256, 2) void mlp_mfma(
    const ushort* __restrict__ Mh, const ushort* __restrict__ Ml,
    const ushort* __restrict__ Bh, const ushort* __restrict__ Bl,
    const float* __restrict__ bm1, const float* __restrict__ Wm2,
    const float* __restrict__ bm2, float* __restrict__ out) {
  __shared__ float red[4][64];
  const int tid = threadIdx.x;
  const int wave = tid >> 6, lane = tid & 63;
  const int g = lane >> 4, c16 = lane & 15;
  const long rowbase = (long)blockIdx.x * 64;
  const size_t arowoff = (size_t)(rowbase + c16) * 128;

  f32x4 acc[4];
#pragma unroll
  for (int rf = 0; rf < 4; ++rf) acc[rf] = (f32x4){0.f, 0.f, 0.f, 0.f};

#pragma unroll
  for (int kc = 0; kc < 4; ++kc) {
    bf16x8 aH[4], aL[4];
    size_t aoff = arowoff + (size_t)kc * 32 + (size_t)g * 8;
#pragma unroll
    for (int rf = 0; rf < 4; ++rf) {
      aH[rf] = *(const bf16x8*)(Mh + aoff + (size_t)rf * 2048);
      aL[rf] = *(const bf16x8*)(Ml + aoff + (size_t)rf * 2048);
    }
    size_t boff = (((size_t)(kc * 4 + wave) * 4 + g) * 16 + c16) * 8;
    bf16x8 bH = *(const bf16x8*)(Bh + boff);
    bf16x8 bL = *(const bf16x8*)(Bl + boff);
#pragma unroll
    for (int rf = 0; rf < 4; ++rf)
      acc[rf] = __builtin_amdgcn_mfma_f32_16x16x32_bf16(aH[rf], bH, acc[rf], 0, 0, 0);
#pragma unroll
    for (int rf = 0; rf < 4; ++rf)
      acc[rf] = __builtin_amdgcn_mfma_f32_16x16x32_bf16(aH[rf], bL, acc[rf], 0, 0, 0);
#pragma unroll
    for (int rf = 0; rf < 4; ++rf)
      acc[rf] = __builtin_amdgcn_mfma_f32_16x16x32_bf16(aL[rf], bH, acc[rf], 0, 0, 0);
  }

  const int c = wave * 16 + c16;
  const float b1 = bm1[c];
  const float w2 = Wm2[c];
#pragma unroll
  for (int rf = 0; rf < 4; ++rf) {
#pragma unroll
    for (int reg = 0; reg < 4; ++reg) {
      float v = acc[rf][reg] + b1;
      v = v > 0.f ? v : 0.01f * v;
      v *= w2;
#pragma unroll
      for (int off = 1; off < 16; off <<= 1) v += __shfl_xor(v, off);
      if (c16 == 0) red[wave][rf * 16 + g * 4 + reg] = v;
    }
  }
  __syncthreads();
  if (tid < 64) {
    long row = rowbase + tid;
    if (row < Nn)
      out[row] = red[0][tid] + red[1][tid] + red[2][tid] + red[3][tid] + bm2[0];
  }
}

extern "C" void kernel_launch(void* const* d_in, const int* in_sizes, int n_in,
                              void* d_out, int out_size, void* d_ws, size_t ws_size,
                              hipStream_t stream) {
  const float* X = (const float*)d_in[0];
  const int* ei = (const int*)d_in[1];
  const float* W0 = (const float*)d_in[2];
  const float* b0 = (const float*)d_in[3];
  const float* Wih = (const float*)d_in[4];
  const float* Whh = (const float*)d_in[5];
  const float* bih = (const float*)d_in[6];
  const float* bhh = (const float*)d_in[7];
  const float* Wm1 = (const float*)d_in[8];
  const float* bm1 = (const float*)d_in[9];
  const float* Wm2 = (const float*)d_in[10];
  const float* bm2 = (const float*)d_in[11];
  float* out = (float*)d_out;

  char* ws = (char*)d_ws;
  size_t off = 0;
  auto alloc = [&](size_t bytes) -> void* {
    void* p = ws + off;
    off = (off + bytes + 255) & ~(size_t)255;
    return p;
  };
  float* h = (float*)alloc((size_t)NP * Hh * 4);
  ushort* Mh = (ushort*)alloc((size_t)NP * Hh * 2);
  ushort* Ml = (ushort*)alloc((size_t)NP * Hh * 2);
  ushort* Ahi = (ushort*)alloc((size_t)NP * 256 * 2);
  ushort* Alo = (ushort*)alloc((size_t)NP * 256 * 2);
  ushort* Bhi = (ushort*)alloc((size_t)8 * 24 * 4 * 16 * 8 * 2);
  ushort* Blo = (ushort*)alloc((size_t)8 * 24 * 4 * 16 * 8 * 2);
  ushort* Bmh = (ushort*)alloc((size_t)1024 * 8 * 2);
  ushort* Bml = (ushort*)alloc((size_t)1024 * 8 * 2);
  float* dis = (float*)alloc((size_t)Nn * 4);
  int* degi = (int*)alloc((size_t)Nn * 4);
  int* cnt = (int*)alloc((size_t)Nn * 4);
  int* rowptr = (int*)alloc((size_t)(Nn + 1) * 4);
  int* cursor = (int*)alloc((size_t)Nn * 4);
  int* bsum = (int*)alloc(512 * 4);
  int* bpre = (int*)alloc(512 * 4);
  int* csr_src = (int*)alloc((size_t)Ee * 4);
  float* csr_w = (float*)alloc((size_t)Ee * 4);
  (void)ws_size;
  (void)in_sizes;
  (void)n_in;
  (void)out_size;

  const int NB = (Nn + 255) / 256;  // 391
  const int EB = (Ee + 255) / 256;  // 2344

  zero_kernel<<<NB, 256, 0, stream>>>(degi, cnt, Nn);
  count_kernel<<<EB, 256, 0, stream>>>(ei, degi, cnt);
  dis_kernel<<<NB, 256, 0, stream>>>(degi, dis);
  scan_partial<<<NB, 256, 0, stream>>>(cnt, bsum);
  scan_bsums<<<1, 512, 0, stream>>>(bsum, bpre, NB);
  scan_final<<<NB, 256, 0, stream>>>(cnt, bpre, rowptr, cursor);
  fill_kernel<<<EB, 256, 0, stream>>>(ei, dis, cursor, csr_src, csr_w);
  pack_kernel<<<48, 256, 0, stream>>>(Wih, Whh, Bhi, Blo);
  pack_mlp<<<4, 256, 0, stream>>>(Wm1, Bmh, Bml);
  h0_kernel<<<(NP * Hh) / 256, 256, 0, stream>>>(X, W0, b0, h, Mh, Ml, Ahi, Alo);

  for (int it = 0; it < 5; ++it) {
    agg_kernel<<<(NP * 32) / 256, 256, 0, stream>>>(h, csr_src, csr_w, rowptr, Ahi, Alo);
    gru_mfma<<<NP / 64, 256, 0, stream>>>(Ahi, Alo, Bhi, Blo, h, Mh, Ml, bih, bhh);
  }

  mlp_mfma<<<NP / 64, 256, 0, stream>>>(Mh, Ml, Bmh, Bml, bm1, Wm2, bm2, out);
}

// Round 4
// 1156.005 us; speedup vs baseline: 5.8755x; 1.1658x over previous
//
#include <hip/hip_runtime.h>

#define Nn 100000
#define Ee 600000
#define Hh 128
#define NP 100096  // padded node rows: multiple of 64

typedef short bf16x8 __attribute__((ext_vector_type(8)));
typedef float f32x4 __attribute__((ext_vector_type(4)));
typedef unsigned short u16x8 __attribute__((ext_vector_type(8)));

static __device__ __forceinline__ float sigmoidf_(float x) {
  return 1.0f / (1.0f + __expf(-x));
}
static __device__ __forceinline__ float tanh_fast(float x) {
  return 1.0f - 2.0f / (__expf(2.0f * x) + 1.0f);
}
// round-to-nearest-even fp32 -> bf16 bits
static __device__ __forceinline__ ushort f2bf(float v) {
  unsigned u = __float_as_uint(v);
  unsigned r = (u + 0x7fffu + ((u >> 16) & 1u)) >> 16;
  return (ushort)r;
}
static __device__ __forceinline__ float bf2f(ushort b) {
  return __uint_as_float(((unsigned)b) << 16);
}
// A fragment-major layout: [tile][kc:8][rf:4][g:4][c16:16][j:8]
static __device__ __forceinline__ size_t fragoff(int tile, int kc, int rf, int g,
                                                 int c16, int j) {
  return (size_t)tile * 16384 + (size_t)kc * 2048 + (size_t)rf * 512 +
         (size_t)g * 128 + (size_t)c16 * 8 + j;
}

__global__ void zero_kernel(int* __restrict__ a, int* __restrict__ b, int n) {
  int i = blockIdx.x * 256 + threadIdx.x;
  if (i < n) { a[i] = 0; b[i] = 0; }
}

__global__ void count_kernel(const int* __restrict__ ei, int* __restrict__ degi,
                             int* __restrict__ cnt) {
  int e = blockIdx.x * 256 + threadIdx.x;
  if (e >= Ee) return;
  int r = ei[e], c = ei[Ee + e];
  atomicAdd(&degi[r], 1);
  atomicAdd(&degi[c], 1);
  atomicAdd(&cnt[c], 1);
}

__global__ void dis_kernel(const int* __restrict__ degi, float* __restrict__ dis) {
  int i = blockIdx.x * 256 + threadIdx.x;
  if (i < Nn) dis[i] = rsqrtf((float)degi[i] + 1.0f);
}

__global__ void scan_partial(const int* __restrict__ cnt, int* __restrict__ bsum) {
  __shared__ int s[256];
  int i = blockIdx.x * 256 + threadIdx.x;
  s[threadIdx.x] = (i < Nn) ? cnt[i] : 0;
  __syncthreads();
  for (int off = 128; off > 0; off >>= 1) {
    if (threadIdx.x < off) s[threadIdx.x] += s[threadIdx.x + off];
    __syncthreads();
  }
  if (threadIdx.x == 0) bsum[blockIdx.x] = s[0];
}

__global__ void scan_bsums(const int* __restrict__ bsum, int* __restrict__ bpre, int nb) {
  __shared__ int s[512];
  int t = threadIdx.x;
  s[t] = (t < nb) ? bsum[t] : 0;
  __syncthreads();
  for (int off = 1; off < 512; off <<= 1) {
    int u = (t >= off) ? s[t - off] : 0;
    __syncthreads();
    s[t] += u;
    __syncthreads();
  }
  if (t < nb) bpre[t] = (t == 0) ? 0 : s[t - 1];
}

__global__ void scan_final(const int* __restrict__ cnt, const int* __restrict__ bpre,
                           int* __restrict__ rowptr, int* __restrict__ cursor) {
  __shared__ int s[256];
  int t = threadIdx.x;
  int i = blockIdx.x * 256 + t;
  int v = (i < Nn) ? cnt[i] : 0;
  s[t] = v;
  __syncthreads();
  for (int off = 1; off < 256; off <<= 1) {
    int u = (t >= off) ? s[t - off] : 0;
    __syncthreads();
    s[t] += u;
    __syncthreads();
  }
  int excl = s[t] - v;
  int base = bpre[blockIdx.x];
  if (i < Nn) { rowptr[i] = base + excl; cursor[i] = base + excl; }
  if (i == Nn - 1) rowptr[Nn] = base + excl + v;
}

__global__ void fill_kernel(const int* __restrict__ ei, const float* __restrict__ dis,
                            int* __restrict__ cursor, int* __restrict__ csr_src,
                            float* __restrict__ csr_w) {
  int e = blockIdx.x * 256 + threadIdx.x;
  if (e >= Ee) return;
  int r = ei[e], c = ei[Ee + e];
  int p = atomicAdd(&cursor[c], 1);
  csr_src[p] = r;
  csr_w[p] = dis[r] * dis[c];
}

// Pack GRU weights into fragment-major split-bf16 (unchanged layout):
// B[kc][fid][g][c16][j], fid = gate*8+f; k = kc*32+g*8+j, col c=(fid&7)*16+c16,
// weight row = gate*128 + c. kc<4 -> Wih, kc>=4 -> Whh.
__global__ void pack_kernel(const float* __restrict__ Wih, const float* __restrict__ Whh,
                            ushort* __restrict__ Bhi, ushort* __restrict__ Blo) {
  int t = blockIdx.x * 256 + threadIdx.x;  // 8*24*4*16 = 12288 threads
  if (t >= 8 * 24 * 4 * 16) return;
  int c16 = t & 15;
  int g = (t >> 4) & 3;
  int fid = (t >> 6) % 24;
  int kc = t / (24 * 64);
  int gate = fid >> 3, f = fid & 7;
  int c = f * 16 + c16;
  int wrow = gate * 128 + c;
  size_t base = (size_t)t * 8;
#pragma unroll
  for (int j = 0; j < 8; ++j) {
    int k = kc * 32 + g * 8 + j;
    float v = (k < 128) ? Wih[wrow * 128 + k] : Whh[wrow * 128 + (k - 128)];
    ushort hi = f2bf(v);
    Bhi[base + j] = hi;
    Blo[base + j] = f2bf(v - bf2f(hi));
  }
}

// Pack MLP W1 (64 x 128): Bm[kc][cf][g][c16][j], c = cf*16+c16, k = kc*32+g*8+j
__global__ void pack_mlp(const float* __restrict__ Wm1, ushort* __restrict__ Bh,
                         ushort* __restrict__ Bl) {
  int t = blockIdx.x * 256 + threadIdx.x;  // 4*4*4*16 = 1024
  if (t >= 1024) return;
  int c16 = t & 15;
  int g = (t >> 4) & 3;
  int cf = (t >> 6) & 3;
  int kc = t >> 8;
  int c = cf * 16 + c16;
  size_t base = (size_t)t * 8;
#pragma unroll
  for (int j = 0; j < 8; ++j) {
    int k = kc * 32 + g * 8 + j;
    float v = Wm1[c * 128 + k];
    ushort hi = f2bf(v);
    Bh[base + j] = hi;
    Bl[base + j] = f2bf(v - bf2f(hi));
  }
}

__global__ void h0_kernel(const float* __restrict__ X, const float* __restrict__ W0,
                          const float* __restrict__ b0, float* __restrict__ h,
                          float* __restrict__ Mfp, ushort* __restrict__ Ahf,
                          ushort* __restrict__ Alf) {
  int t = blockIdx.x * 256 + threadIdx.x;
  int i = t >> 7, d = t & 127;
  if (i >= NP) return;
  float v = 0.0f;
  if (i < Nn) {
    float x0 = X[i * 3 + 0], x1 = X[i * 3 + 1], x2 = X[i * 3 + 2];
    v = fmaf(x0, W0[d * 3 + 0], fmaf(x1, W0[d * 3 + 1], fmaf(x2, W0[d * 3 + 2], b0[d])));
    v = v > 0.0f ? v : 0.01f * v;
  }
  size_t gi = (size_t)i * Hh + d;
  h[gi] = v;
  Mfp[gi] = -1e30f;
  int tile = i >> 6, rf = (i >> 4) & 3, c16 = i & 15;
  int kc = 4 + (d >> 5), g = (d >> 3) & 3, j = d & 7;
  size_t o = fragoff(tile, kc, rf, g, c16, j);
  ushort hb = f2bf(v);
  Ahf[o] = hb;
  Alf[o] = f2bf(v - bf2f(hb));
}

// Gather: 8 lanes per node, 16 dims each; writes split-bf16 into fragment-major
// A slots kc 0..3 (k = d), as ushort8 (16B) stores that wave-coalesce.
__global__ __launch_bounds__(256) void agg_kernel(const float* __restrict__ h,
    const int* __restrict__ csr_src, const float* __restrict__ csr_w,
    const int* __restrict__ rowptr, ushort* __restrict__ Ahf, ushort* __restrict__ Alf) {
  int t = blockIdx.x * 256 + threadIdx.x;
  int node = t >> 3, l8 = t & 7;
  if (node >= NP) return;
  float acc[16];
#pragma unroll
  for (int m = 0; m < 16; ++m) acc[m] = 0.0f;
  if (node < Nn) {
    int e0 = rowptr[node], e1 = rowptr[node + 1];
    const float* hb = h + l8 * 16;
    for (int e = e0; e < e1; ++e) {
      int src = csr_src[e];
      float w = csr_w[e];
      const float4* p = (const float4*)(hb + (size_t)src * Hh);
      float4 v0 = p[0], v1 = p[1], v2 = p[2], v3 = p[3];
      acc[0] = fmaf(w, v0.x, acc[0]);  acc[1] = fmaf(w, v0.y, acc[1]);
      acc[2] = fmaf(w, v0.z, acc[2]);  acc[3] = fmaf(w, v0.w, acc[3]);
      acc[4] = fmaf(w, v1.x, acc[4]);  acc[5] = fmaf(w, v1.y, acc[5]);
      acc[6] = fmaf(w, v1.z, acc[6]);  acc[7] = fmaf(w, v1.w, acc[7]);
      acc[8] = fmaf(w, v2.x, acc[8]);  acc[9] = fmaf(w, v2.y, acc[9]);
      acc[10] = fmaf(w, v2.z, acc[10]); acc[11] = fmaf(w, v2.w, acc[11]);
      acc[12] = fmaf(w, v3.x, acc[12]); acc[13] = fmaf(w, v3.y, acc[13]);
      acc[14] = fmaf(w, v3.z, acc[14]); acc[15] = fmaf(w, v3.w, acc[15]);
    }
  }
  // d = l8*16 + m; kc = l8>>1; g = (l8&1)*2 + (m>>3); j = m&7
  int tile = node >> 6, rf = (node >> 4) & 3, c16 = node & 15;
  int kc = l8 >> 1;
#pragma unroll
  for (int gg = 0; gg < 2; ++gg) {
    int g = ((l8 & 1) << 1) + gg;
    u16x8 vh, vl;
#pragma unroll
    for (int j = 0; j < 8; ++j) {
      float v = acc[gg * 8 + j];
      ushort hb = f2bf(v);
      vh[j] = hb;
      vl[j] = f2bf(v - bf2f(hb));
    }
    size_t o = fragoff(tile, kc, rf, g, c16, 0);
    *(u16x8*)(Ahf + o) = vh;
    *(u16x8*)(Alf + o) = vl;
  }
}

// ---- MFMA GRU ----
#define DO_GATE(GB, ACC)                                                              \
  {                                                                                   \
    bf16x8 bH[2], bL[2];                                                              \
    _Pragma("unroll") for (int cf = 0; cf < 2; ++cf) {                                \
      size_t boff = (((size_t)(kc * 24 + (GB)*8 + wave * 2 + cf) * 4 + g) * 16 + c16) * 8; \
      bH[cf] = *(const bf16x8*)(Bhi + boff);                                          \
      bL[cf] = *(const bf16x8*)(Blo + boff);                                          \
    }                                                                                 \
    _Pragma("unroll") for (int cf = 0; cf < 2; ++cf)                                  \
        _Pragma("unroll") for (int rf = 0; rf < 4; ++rf)                              \
            ACC[rf][cf] = __builtin_amdgcn_mfma_f32_16x16x32_bf16(aH[rf], bH[cf], ACC[rf][cf], 0, 0, 0); \
    _Pragma("unroll") for (int cf = 0; cf < 2; ++cf)                                  \
        _Pragma("unroll") for (int rf = 0; rf < 4; ++rf)                              \
            ACC[rf][cf] = __builtin_amdgcn_mfma_f32_16x16x32_bf16(aH[rf], bL[cf], ACC[rf][cf], 0, 0, 0); \
    _Pragma("unroll") for (int cf = 0; cf < 2; ++cf)                                  \
        _Pragma("unroll") for (int rf = 0; rf < 4; ++rf)                              \
            ACC[rf][cf] = __builtin_amdgcn_mfma_f32_16x16x32_bf16(aL[rf], bH[cf], ACC[rf][cf], 0, 0, 0); \
  }

#define KC_STEP(ACCN)                                                                 \
  {                                                                                   \
    bf16x8 aH[4], aL[4];                                                              \
    _Pragma("unroll") for (int rf = 0; rf < 4; ++rf) {                                \
      size_t ao = abase + (size_t)kc * 2048 + (size_t)rf * 512;                       \
      aH[rf] = *(const bf16x8*)(Ahf + ao);                                            \
      aL[rf] = *(const bf16x8*)(Alf + ao);                                            \
    }                                                                                 \
    DO_GATE(0, accR)                                                                  \
    DO_GATE(1, accZ)                                                                  \
    DO_GATE(2, ACCN)                                                                  \
  }

__global__ __launch_bounds__(256, 2) void gru_mfma(
    ushort* __restrict__ Ahf, ushort* __restrict__ Alf,
    const ushort* __restrict__ Bhi, const ushort* __restrict__ Blo,
    float* __restrict__ h, float* __restrict__ Mfp,
    const float* __restrict__ bih, const float* __restrict__ bhh) {
  const int tid = threadIdx.x;
  const int wave = tid >> 6, lane = tid & 63;
  const int g = lane >> 4, c16 = lane & 15;
  const int tile = blockIdx.x;
  const long rowbase = (long)tile * 64;
  const size_t abase = (size_t)tile * 16384 + (size_t)g * 128 + (size_t)c16 * 8;

  f32x4 accR[4][2], accZ[4][2], accXN[4][2], accHN[4][2];
#pragma unroll
  for (int rf = 0; rf < 4; ++rf)
#pragma unroll
    for (int cf = 0; cf < 2; ++cf) {
      accR[rf][cf] = (f32x4){0.f, 0.f, 0.f, 0.f};
      accZ[rf][cf] = (f32x4){0.f, 0.f, 0.f, 0.f};
      accXN[rf][cf] = (f32x4){0.f, 0.f, 0.f, 0.f};
      accHN[rf][cf] = (f32x4){0.f, 0.f, 0.f, 0.f};
    }

#pragma unroll
  for (int kc = 0; kc < 4; ++kc) KC_STEP(accXN)
#pragma unroll
  for (int kc = 4; kc < 8; ++kc) KC_STEP(accHN)

#pragma unroll
  for (int cf = 0; cf < 2; ++cf) {
    const int c = (wave * 2 + cf) * 16 + c16;
    const float br = bih[c] + bhh[c];
    const float bz = bih[128 + c] + bhh[128 + c];
    const float bxn = bih[256 + c];
    const float bhn = bhh[256 + c];
    const int gp = (cf * 2 + (c16 >> 3)) & 3;
    const int jp = c16 & 7;
#pragma unroll
    for (int rf = 0; rf < 4; ++rf) {
      const long row0 = rowbase + rf * 16 + g * 4;
      const size_t ab = (size_t)tile * 16384 + (size_t)(4 + wave) * 2048 +
                        (size_t)rf * 512 + (size_t)gp * 128 + jp;
#pragma unroll
      for (int reg = 0; reg < 4; ++reg) {
        const long row = row0 + reg;
        float rr = sigmoidf_(accR[rf][cf][reg] + br);
        float zz = sigmoidf_(accZ[rf][cf][reg] + bz);
        float nn = tanh_fast(accXN[rf][cf][reg] + bxn + rr * (accHN[rf][cf][reg] + bhn));
        size_t gi = (size_t)row * Hh + c;
        float hold = h[gi];
        float hnew = (1.0f - zz) * nn + zz * hold;
        h[gi] = hnew;
        Mfp[gi] = fmaxf(Mfp[gi], hnew);
        ushort hb = f2bf(hnew);
        size_t ao = ab + (size_t)(g * 4 + reg) * 8;
        Ahf[ao] = hb;
        Alf[ao] = f2bf(hnew - bf2f(hb));
      }
    }
  }
}

// ---- MFMA MLP ----
// Block = 64 nodes, 4 waves; wave w owns cols [16w, 16w+16) of hid (64 cols).
// Splits fp32 hmax to bf16 hi/lo on the fly.
__global__ __launch_bounds__(256, 2) void mlp_mfma(
    const float* __restrict__ Mfp,
    const ushort* __restrict__ Bh, const ushort* __restrict__ Bl,
    const float* __restrict__ bm1, const float* __restrict__ Wm2,
    const float* __restrict__ bm2, float* __restrict__ out) {
  __shared__ float red[4][64];
  const int tid = threadIdx.x;
  const int wave = tid >> 6, lane = tid & 63;
  const int g = lane >> 4, c16 = lane & 15;
  const long rowbase = (long)blockIdx.x * 64;

  f32x4 acc[4];
#pragma unroll
  for (int rf = 0; rf < 4; ++rf) acc[rf] = (f32x4){0.f, 0.f, 0.f, 0.f};

#pragma unroll
  for (int kc = 0; kc < 4; ++kc) {
    bf16x8 aH[4], aL[4];
#pragma unroll
    for (int rf = 0; rf < 4; ++rf) {
      const float* mp = Mfp + (size_t)(rowbase + rf * 16 + c16) * Hh + kc * 32 + g * 8;
      float4 f0 = *(const float4*)mp;
      float4 f1 = *(const float4*)(mp + 4);
      float v[8] = {f0.x, f0.y, f0.z, f0.w, f1.x, f1.y, f1.z, f1.w};
      u16x8 vh, vl;
#pragma unroll
      for (int m = 0; m < 8; ++m) {
        ushort hb = f2bf(v[m]);
        vh[m] = hb;
        vl[m] = f2bf(v[m] - bf2f(hb));
      }
      aH[rf] = (bf16x8)vh;
      aL[rf] = (bf16x8)vl;
    }
    size_t boff = (((size_t)(kc * 4 + wave) * 4 + g) * 16 + c16) * 8;
    bf16x8 bH = *(const bf16x8*)(Bh + boff);
    bf16x8 bL = *(const bf16x8*)(Bl + boff);
#pragma unroll
    for (int rf = 0; rf < 4; ++rf)
      acc[rf] = __builtin_amdgcn_mfma_f32_16x16x32_bf16(aH[rf], bH, acc[rf], 0, 0, 0);
#pragma unroll
    for (int rf = 0; rf < 4; ++rf)
      acc[rf] = __builtin_amdgcn_mfma_f32_16x16x32_bf16(aH[rf], bL, acc[rf], 0, 0, 0);
#pragma unroll
    for (int rf = 0; rf < 4; ++rf)
      acc[rf] = __builtin_amdgcn_mfma_f32_16x16x32_bf16(aL[rf], bH, acc[rf], 0, 0, 0);
  }

  const int c = wave * 16 + c16;
  const float b1 = bm1[c];
  const float w2 = Wm2[c];
#pragma unroll
  for (int rf = 0; rf < 4; ++rf) {
#pragma unroll
    for (int reg = 0; reg < 4; ++reg) {
      float v = acc[rf][reg] + b1;
      v = v > 0.f ? v : 0.01f * v;
      v *= w2;
#pragma unroll
      for (int off = 1; off < 16; off <<= 1) v += __shfl_xor(v, off);
      if (c16 == 0) red[wave][rf * 16 + g * 4 + reg] = v;
    }
  }
  __syncthreads();
  if (tid < 64) {
    long row = rowbase + tid;
    if (row < Nn)
      out[row] = red[0][tid] + red[1][tid] + red[2][tid] + red[3][tid] + bm2[0];
  }
}

extern "C" void kernel_launch(void* const* d_in, const int* in_sizes, int n_in,
                              void* d_out, int out_size, void* d_ws, size_t ws_size,
                              hipStream_t stream) {
  const float* X = (const float*)d_in[0];
  const int* ei = (const int*)d_in[1];
  const float* W0 = (const float*)d_in[2];
  const float* b0 = (const float*)d_in[3];
  const float* Wih = (const float*)d_in[4];
  const float* Whh = (const float*)d_in[5];
  const float* bih = (const float*)d_in[6];
  const float* bhh = (const float*)d_in[7];
  const float* Wm1 = (const float*)d_in[8];
  const float* bm1 = (const float*)d_in[9];
  const float* Wm2 = (const float*)d_in[10];
  const float* bm2 = (const float*)d_in[11];
  float* out = (float*)d_out;

  char* ws = (char*)d_ws;
  size_t off = 0;
  auto alloc = [&](size_t bytes) -> void* {
    void* p = ws + off;
    off = (off + bytes + 255) & ~(size_t)255;
    return p;
  };
  float* h = (float*)alloc((size_t)NP * Hh * 4);
  float* Mfp = (float*)alloc((size_t)NP * Hh * 4);
  ushort* Ahf = (ushort*)alloc((size_t)(NP / 64) * 16384 * 2);
  ushort* Alf = (ushort*)alloc((size_t)(NP / 64) * 16384 * 2);
  ushort* Bhi = (ushort*)alloc((size_t)8 * 24 * 4 * 16 * 8 * 2);
  ushort* Blo = (ushort*)alloc((size_t)8 * 24 * 4 * 16 * 8 * 2);
  ushort* Bmh = (ushort*)alloc((size_t)1024 * 8 * 2);
  ushort* Bml = (ushort*)alloc((size_t)1024 * 8 * 2);
  float* dis = (float*)alloc((size_t)Nn * 4);
  int* degi = (int*)alloc((size_t)Nn * 4);
  int* cnt = (int*)alloc((size_t)Nn * 4);
  int* rowptr = (int*)alloc((size_t)(Nn + 1) * 4);
  int* cursor = (int*)alloc((size_t)Nn * 4);
  int* bsum = (int*)alloc(512 * 4);
  int* bpre = (int*)alloc(512 * 4);
  int* csr_src = (int*)alloc((size_t)Ee * 4);
  float* csr_w = (float*)alloc((size_t)Ee * 4);
  (void)ws_size;
  (void)in_sizes;
  (void)n_in;
  (void)out_size;

  const int NB = (Nn + 255) / 256;  // 391
  const int EB = (Ee + 255) / 256;  // 2344

  zero_kernel<<<NB, 256, 0, stream>>>(degi, cnt, Nn);
  count_kernel<<<EB, 256, 0, stream>>>(ei, degi, cnt);
  dis_kernel<<<NB, 256, 0, stream>>>(degi, dis);
  scan_partial<<<NB, 256, 0, stream>>>(cnt, bsum);
  scan_bsums<<<1, 512, 0, stream>>>(bsum, bpre, NB);
  scan_final<<<NB, 256, 0, stream>>>(cnt, bpre, rowptr, cursor);
  fill_kernel<<<EB, 256, 0, stream>>>(ei, dis, cursor, csr_src, csr_w);
  pack_kernel<<<48, 256, 0, stream>>>(Wih, Whh, Bhi, Blo);
  pack_mlp<<<4, 256, 0, stream>>>(Wm1, Bmh, Bml);
  h0_kernel<<<(NP * Hh) / 256, 256, 0, stream>>>(X, W0, b0, h, Mfp, Ahf, Alf);

  for (int it = 0; it < 5; ++it) {
    agg_kernel<<<(NP * 8) / 256, 256, 0, stream>>>(h, csr_src, csr_w, rowptr, Ahf, Alf);
    gru_mfma<<<NP / 64, 256, 0, stream>>>(Ahf, Alf, Bhi, Blo, h, Mfp, bih, bhh);
  }

  mlp_mfma<<<NP / 64, 256, 0, stream>>>(Mfp, Bmh, Bml, bm1, Wm2, bm2, out);
}